// Round 9
// baseline (777.205 us; speedup 1.0000x reference)
//
#include <hip/hip_runtime.h>

// WaveCell round-15: ONE WAVE PER BLOCK, ZERO BARRIERS.
// Evidence r6-r14: ~1.1us per time step invariant under VALU cuts, store
// drains, unroll changes; +25% when work doubled. The cost is the cross-wave
// chain: 7-wave barrier convoy (42 ds-ops through one LDS pipe, ds latency,
// write drain, lgkmcnt(0), s_barrier resync at 1.75 waves/SIMD). Fix: one
// wave64 owns the whole 56x56 tile -> lockstep, ping/pong needs only
// lgkmcnt(0). Lane (rs=lane>>3, lg=lane&7) owns 7 rows (lr=rs+8s, s=0..6;
// covers 0..55 exactly, once each) x 8 cols in registers.
// Per step: 28 ds_read_b128 (up/dn) + 14 ds_write_b128 + 14 shuffles + VALU.
// Register diet: D == 1+E exactly ((1e6+500b)*ai==1) -> val = y + E*(y-p)
// + G*lap; E,G arrays only (~220 VGPR, fits launch_bounds(64,1)).
// Infra: PROVEN classic 16 launches (r13's failure was the fence-free
// handshake, not math - r14 isolated). Global I/O, halo, til, contamination
// analysis identical to r8.

#define NXg 192
#define NYg 192
#define BATCH 4
#define TSTEPS 256
#define CELLS (NXg * NYg)

#define TS 24
#define KSTEP 16
#define EXT 56                   // TS + 2*KSTEP
#define LROWS 58                 // guard row 0, data rows 1..56, guard 57
#define LPITCH 68                // dwords/row: 4 pad | 56 data | 8 pad
#define LSZ (LROWS * LPITCH)
#define NSLOT 7                  // rows per lane

#define SRC_X 96
#define SRC_Y 32

// val = y + E*(y - p) + G*(up+dn+lf+rt-4y)
#define CELL(dst, up_, dn_, lf_, rt_, E_, G_, y_, p_)                  \
  {                                                                    \
    float s_ = fmaf(-4.0f, y_, (up_ + dn_) + (lf_ + rt_));             \
    dst = fmaf(G_, s_, fmaf(E_, (y_ - p_), y_));                       \
  }

__global__ __launch_bounds__(64, 1) void wave_kernel(
    const float* __restrict__ cgp, const float* __restrict__ bgp,
    const float* __restrict__ x, float* __restrict__ out, int t0) {
  __shared__ float buf0[LSZ];
  __shared__ float buf1[LSZ];
  __shared__ float xsL[KSTEP];

  const int lane = threadIdx.x;   // 0..63 (one wave)
  const int rs = lane >> 3;       // row slot base 0..7
  const int lg = lane & 7;        // col group; lg==7 is the zero lane
  const int bcol = blockIdx.x;    // 0..7
  const int brow = blockIdx.y;    // 0..7
  const int bb = blockIdx.z;      // 0..3
  const int r0 = brow * TS - KSTEP;
  const int c0 = bcol * TS - KSTEP;
  const int obase = bb * TSTEPS * CELLS;
  const float inv_h2 = (float)(1.0 / (2.0 * 1.01 * 1.01 * 1.0e-3 * 1.0e-3));

  const int gc = c0 + 8 * lg;     // multiple of 8; never straddles the edge
  const bool colOK = (lg < 7) && (gc >= 0) && (gc < NYg);
  const bool hs = (SRC_X >= r0) && (SRC_X < r0 + EXT) &&
                  (SRC_Y >= c0) && (SRC_Y < c0 + EXT);

  const float4 z4 = make_float4(0.f, 0.f, 0.f, 0.f);

  // Source column mask (row factor fs[s] applied per slot).
  float4 smc0 = z4, smc1 = z4;
  if (colOK) {
    smc0.x = (gc + 0 == SRC_Y) ? 1.0f : 0.0f;
    smc0.y = (gc + 1 == SRC_Y) ? 1.0f : 0.0f;
    smc0.z = (gc + 2 == SRC_Y) ? 1.0f : 0.0f;
    smc0.w = (gc + 3 == SRC_Y) ? 1.0f : 0.0f;
    smc1.x = (gc + 4 == SRC_Y) ? 1.0f : 0.0f;
    smc1.y = (gc + 5 == SRC_Y) ? 1.0f : 0.0f;
    smc1.z = (gc + 6 == SRC_Y) ? 1.0f : 0.0f;
    smc1.w = (gc + 7 == SRC_Y) ? 1.0f : 0.0f;
  }

  // ---- Per-slot setup: rows lr = rs + 8*s  (s=0..6 covers 0..55 once). ----
  int offs[NSLOT];      // LDS dword offset of own row
  int gofs[NSLOT];      // global cell offset (0 if invalid)
  bool idv[NSLOT];      // lane/row inside domain
  bool tils[NSLOT];     // store mask (rows 16..39 <=> s in {2,3,4})
  float fs[NSLOT];      // source row factor
  float4 E[NSLOT][2], G[NSLOT][2];
  float4 yc[NSLOT][2], yp[NSLOT][2];

#pragma unroll
  for (int s = 0; s < NSLOT; ++s) {
    const int lr = rs + 8 * s;          // 0..55
    const int gr = r0 + lr;
    const bool idr = colOK && (gr >= 0) && (gr < NXg);
    idv[s] = idr;
    gofs[s] = idr ? (gr * NYg + gc) : 0;
    offs[s] = (lr + 1) * LPITCH + 4 + 8 * lg;
    tils[s] = (s >= 2) && (s <= 4) && (lg >= 2) && (lg < 5);
    fs[s] = (gr == SRC_X) ? 1.0f : 0.0f;
    E[s][0] = z4; E[s][1] = z4; G[s][0] = z4; G[s][1] = z4;
    yc[s][0] = z4; yc[s][1] = z4; yp[s][0] = z4; yp[s][1] = z4;
    if (idr) {
      float4 cv0 = *(const float4*)(cgp + gofs[s]);
      float4 cv1 = *(const float4*)(cgp + gofs[s] + 4);
      float4 bv0 = *(const float4*)(bgp + gofs[s]);
      float4 bv1 = *(const float4*)(bgp + gofs[s] + 4);
      float ai;
      ai = 1.0f / (1.0e6f + 500.0f * bv0.x);
      E[s][0].x = (1.0e6f - 500.0f * bv0.x) * ai; G[s][0].x = cv0.x * cv0.x * inv_h2 * ai;
      ai = 1.0f / (1.0e6f + 500.0f * bv0.y);
      E[s][0].y = (1.0e6f - 500.0f * bv0.y) * ai; G[s][0].y = cv0.y * cv0.y * inv_h2 * ai;
      ai = 1.0f / (1.0e6f + 500.0f * bv0.z);
      E[s][0].z = (1.0e6f - 500.0f * bv0.z) * ai; G[s][0].z = cv0.z * cv0.z * inv_h2 * ai;
      ai = 1.0f / (1.0e6f + 500.0f * bv0.w);
      E[s][0].w = (1.0e6f - 500.0f * bv0.w) * ai; G[s][0].w = cv0.w * cv0.w * inv_h2 * ai;
      ai = 1.0f / (1.0e6f + 500.0f * bv1.x);
      E[s][1].x = (1.0e6f - 500.0f * bv1.x) * ai; G[s][1].x = cv1.x * cv1.x * inv_h2 * ai;
      ai = 1.0f / (1.0e6f + 500.0f * bv1.y);
      E[s][1].y = (1.0e6f - 500.0f * bv1.y) * ai; G[s][1].y = cv1.y * cv1.y * inv_h2 * ai;
      ai = 1.0f / (1.0e6f + 500.0f * bv1.z);
      E[s][1].z = (1.0e6f - 500.0f * bv1.z) * ai; G[s][1].z = cv1.z * cv1.z * inv_h2 * ai;
      ai = 1.0f / (1.0e6f + 500.0f * bv1.w);
      E[s][1].w = (1.0e6f - 500.0f * bv1.w) * ai; G[s][1].w = cv1.w * cv1.w * inv_h2 * ai;
      if (t0 > 0) {
        const float* o1 = out + obase + (t0 - 1) * CELLS;
        const float* o2 = out + obase + (t0 - 2) * CELLS;
        yc[s][0] = *(const float4*)(o1 + gofs[s]);
        yc[s][1] = *(const float4*)(o1 + gofs[s] + 4);
        yp[s][0] = *(const float4*)(o2 + gofs[s]);
        yp[s][1] = *(const float4*)(o2 + gofs[s] + 4);
      }
    }
  }

  // Source series for this launch -> LDS (rolled loop needs runtime index).
  if (lane < 4) {
    float4 a = ((const float4*)(x + bb * TSTEPS + t0))[lane];
    *(float4*)&xsL[4 * lane] = a;
  }

  // Zero guard rows 0 and 57 (full 68 dwords incl. pads), both buffers.
  for (int i = lane; i < 2 * LPITCH; i += 64) {
    const int row = (i < LPITCH) ? 0 : (LROWS - 1);
    const int cidx = i % LPITCH;
    buf0[row * LPITCH + cidx] = 0.f;
    buf1[row * LPITCH + cidx] = 0.f;
  }

  // Scatter y(t0-1) into buf0 data rows (lg==7 writes zeros into right pad).
#pragma unroll
  for (int s = 0; s < NSLOT; ++s) {
    *(float4*)&buf0[offs[s]] = yc[s][0];
    *(float4*)&buf0[offs[s] + 4] = yc[s][1];
  }

  float* ping = buf0;
  float* pong = buf1;

  // ---- 16 time steps, single wave, NO barriers (lockstep + lgkmcnt). ----
#pragma clang loop unroll(disable)
  for (int j = 0; j < KSTEP; ++j) {
    // Order: previous step's pong writes (and prologue scatter / xsL / guard
    // zeroing on j==0) complete before this step's reads.
    asm volatile("s_waitcnt lgkmcnt(0)" ::: "memory");
    const float xt = xsL[j];
    float* op = out + obase + (t0 + j) * CELLS;

#pragma unroll
    for (int s = 0; s < NSLOT; ++s) {
      float4 up0 = *(float4*)&ping[offs[s] - LPITCH];
      float4 up1 = *(float4*)&ping[offs[s] - LPITCH + 4];
      float4 dn0 = *(float4*)&ping[offs[s] + LPITCH];
      float4 dn1 = *(float4*)&ping[offs[s] + LPITCH + 4];

      // Left/right neighbors from adjacent lanes' registers (same row set).
      float lq = __shfl_up(yc[s][1].w, 1);
      lq = (lg == 0) ? 0.0f : lq;          // tile's left edge -> 0
      float rq = __shfl_down(yc[s][0].x, 1);
      rq = (lg == 7) ? 0.0f : rq;          // lane lg7+1 is another row set!

      float4 v0, v1;
      CELL(v0.x, up0.x, dn0.x, lq,         yc[s][0].y, E[s][0].x, G[s][0].x, yc[s][0].x, yp[s][0].x);
      CELL(v0.y, up0.y, dn0.y, yc[s][0].x, yc[s][0].z, E[s][0].y, G[s][0].y, yc[s][0].y, yp[s][0].y);
      CELL(v0.z, up0.z, dn0.z, yc[s][0].y, yc[s][0].w, E[s][0].z, G[s][0].z, yc[s][0].z, yp[s][0].z);
      CELL(v0.w, up0.w, dn0.w, yc[s][0].z, yc[s][1].x, E[s][0].w, G[s][0].w, yc[s][0].w, yp[s][0].w);
      CELL(v1.x, up1.x, dn1.x, yc[s][0].w, yc[s][1].y, E[s][1].x, G[s][1].x, yc[s][1].x, yp[s][1].x);
      CELL(v1.y, up1.y, dn1.y, yc[s][1].x, yc[s][1].z, E[s][1].y, G[s][1].y, yc[s][1].y, yp[s][1].y);
      CELL(v1.z, up1.z, dn1.z, yc[s][1].y, yc[s][1].w, E[s][1].z, G[s][1].z, yc[s][1].z, yp[s][1].z);
      CELL(v1.w, up1.w, dn1.w, yc[s][1].z, rq,         E[s][1].w, G[s][1].w, yc[s][1].w, yp[s][1].w);

      if (hs) {  // uniform per block
        const float fx = fs[s] * xt;
        v0.x = fmaf(smc0.x, fx, v0.x);
        v0.y = fmaf(smc0.y, fx, v0.y);
        v0.z = fmaf(smc0.z, fx, v0.z);
        v0.w = fmaf(smc0.w, fx, v0.w);
        v1.x = fmaf(smc1.x, fx, v1.x);
        v1.y = fmaf(smc1.y, fx, v1.y);
        v1.z = fmaf(smc1.z, fx, v1.z);
        v1.w = fmaf(smc1.w, fx, v1.w);
      }

      // Output store (plain; drains at kernel end / launch boundary).
      if (tils[s]) {
        *(float4*)(op + gofs[s]) = v0;
        *(float4*)(op + gofs[s] + 4) = v1;
      }

      // Publish to pong; rotate register state.
      *(float4*)&pong[offs[s]] = v0;
      *(float4*)&pong[offs[s] + 4] = v1;
      yp[s][0] = yc[s][0]; yp[s][1] = yc[s][1];
      yc[s][0] = v0;       yc[s][1] = v1;
    }

    float* t_ = ping; ping = pong; pong = t_;
  }
}

extern "C" void kernel_launch(void* const* d_in, const int* in_sizes, int n_in,
                              void* d_out, int out_size, void* d_ws,
                              size_t ws_size, hipStream_t stream) {
  const float* x = (const float*)d_in[0];  // [B, T, 1]
  const float* c = (const float*)d_in[1];  // [192,192]
  const float* b = (const float*)d_in[2];  // [192,192]
  float* out = (float*)d_out;              // [B, T, 192, 192]

  dim3 grid(NXg / TS, NYg / TS, BATCH);    // 8 x 8 x 4 = 256 blocks, 1 wave each
  for (int t0 = 0; t0 < TSTEPS; t0 += KSTEP) {
    wave_kernel<<<grid, 64, 0, stream>>>(c, b, x, out, t0);
  }
}

// Round 10
// 346.469 us; speedup vs baseline: 2.2432x; 2.2432x over previous
//
#include <hip/hip_runtime.h>

// WaveCell round-16: 2 BLOCKS PER CU (row-split tiles). r15's 1-wave probe
// (777us, VGPR spills + zero TLP) + the r6-r14 invariance of ~1.1us/step to
// all work reduction says the per-step cost is STALL (ds latency + barrier
// convoy + low-clock), which is hidden by MORE concurrent waves. r8's grid
// was exactly 1 block/CU = one exposed convoy. This round: TS 12x24 ->
// 8x16x4 = 512 blocks = 2 independent convoys/CU interleaving their stalls.
// Per block: EXT 44 rows x 56 cols, 352 threads (5.5 waves), LDS 25KB.
// Body is byte-for-byte the proven r8 structure: 16 classic launches,
// software-pipelined sc-less stores, lgkm-only step barriers, fused 7-op
// cell, uniform source guard, trapezoid row-gating (alive = [j+1, 42-j],
// output rows 16..27), masked lg==7 shuffle.

#define NXg 192
#define NYg 192
#define BATCH 4
#define TSTEPS 256
#define CELLS (NXg * NYg)

#define TSR 12                  // output tile rows
#define TSC 24                  // output tile cols
#define KSTEP 16                // time steps per launch
#define EXTR 44                 // TSR + 2*KSTEP (rows)
#define EXTC 56                 // TSC + 2*KSTEP (cols)
#define LROWS (EXTR + 2)        // guard row 0 and 45 (never read: row gating)
#define LPITCH 68               // dwords/row: 4 pad | 56 data | 8 pad
#define LSZ (LROWS * LPITCH)
#define NTHREADS (EXTR * 8)     // 44 rows x 8 lanes = 352 threads (5.5 waves)

#define SRC_X 96
#define SRC_Y 32

__global__ __launch_bounds__(NTHREADS) void wave_tile_kernel(
    const float* __restrict__ cgp, const float* __restrict__ bgp,
    const float* __restrict__ x, float* __restrict__ out, int t0) {
  __shared__ float buf0[LSZ];
  __shared__ float buf1[LSZ];

  const int tid = threadIdx.x;
  const int lr = tid >> 3;      // local row 0..43
  const int lg = tid & 7;       // 8-wide group in row; lg==7 is the zero lane
  const int bcol = blockIdx.x;  // 0..7
  const int brow = blockIdx.y;  // 0..15
  const int bb = blockIdx.z;    // 0..3
  const int r0 = brow * TSR - KSTEP;
  const int c0 = bcol * TSC - KSTEP;
  const int obase = bb * TSTEPS * CELLS;
  const float inv_h2 = (float)(1.0 / (2.0 * 1.01 * 1.01 * 1.0e-3 * 1.0e-3));

  const int gr = r0 + lr;
  const int gc = c0 + 8 * lg;  // multiple of 8; never straddles domain edge
  const bool id = (lg < 7) && (gr >= 0) && (gr < NXg) && (gc >= 0) && (gc < NYg);
  const bool til = (lr >= KSTEP) && (lr < KSTEP + TSR) && (lg >= 2) && (lg < 5);
  // Does this block's EXT tile contain the point source? (uniform per block)
  const bool hs = (SRC_X >= r0) && (SRC_X < r0 + EXTR) &&
                  (SRC_Y >= c0) && (SRC_Y < c0 + EXTC);
  const int gofs = id ? (gr * NYg + gc) : 0;

  const float4 z4 = make_float4(0.f, 0.f, 0.f, 0.f);

  // ---- 1. Issue ALL global loads up front (latency overlaps the rest). ----
  float4 cv0 = z4, cv1 = z4, bv0 = z4, bv1 = z4;
  float4 yc0 = z4, yc1 = z4, yp0 = z4, yp1 = z4;
  if (id) {
    cv0 = *(const float4*)(cgp + gofs);
    cv1 = *(const float4*)(cgp + gofs + 4);
    bv0 = *(const float4*)(bgp + gofs);
    bv1 = *(const float4*)(bgp + gofs + 4);
    if (t0 > 0) {
      yc0 = *(const float4*)(out + obase + (t0 - 1) * CELLS + gofs);
      yc1 = *(const float4*)(out + obase + (t0 - 1) * CELLS + gofs + 4);
      yp0 = *(const float4*)(out + obase + (t0 - 2) * CELLS + gofs);
      yp1 = *(const float4*)(out + obase + (t0 - 2) * CELLS + gofs + 4);
    }
  }
  float xs[KSTEP];
  {
    const float4* xp = (const float4*)(x + bb * TSTEPS + t0);
    float4 a0 = xp[0], a1 = xp[1], a2 = xp[2], a3 = xp[3];
    xs[0] = a0.x; xs[1] = a0.y; xs[2] = a0.z; xs[3] = a0.w;
    xs[4] = a1.x; xs[5] = a1.y; xs[6] = a1.z; xs[7] = a1.w;
    xs[8] = a2.x; xs[9] = a2.y; xs[10] = a2.z; xs[11] = a2.w;
    xs[12] = a3.x; xs[13] = a3.y; xs[14] = a3.z; xs[15] = a3.w;
  }

  // ---- 2. Fused coefficients (overlaps load latency). ----
  // val = Dc*yc - Ey*yp + G*(sum4 - 4*yc) [+ sm*xt]
  float4 Dc0 = z4, Dc1 = z4, Ey0 = z4, Ey1 = z4, G0 = z4, G1 = z4;
  float4 sm0 = z4, sm1 = z4;
  if (id) {
    float ai;
    ai = 1.0f / (1.0e6f + 500.0f * bv0.x);
    Dc0.x = 2.0e6f * ai; Ey0.x = (1.0e6f - 500.0f * bv0.x) * ai;
    G0.x = (cv0.x * cv0.x) * inv_h2 * ai;
    ai = 1.0f / (1.0e6f + 500.0f * bv0.y);
    Dc0.y = 2.0e6f * ai; Ey0.y = (1.0e6f - 500.0f * bv0.y) * ai;
    G0.y = (cv0.y * cv0.y) * inv_h2 * ai;
    ai = 1.0f / (1.0e6f + 500.0f * bv0.z);
    Dc0.z = 2.0e6f * ai; Ey0.z = (1.0e6f - 500.0f * bv0.z) * ai;
    G0.z = (cv0.z * cv0.z) * inv_h2 * ai;
    ai = 1.0f / (1.0e6f + 500.0f * bv0.w);
    Dc0.w = 2.0e6f * ai; Ey0.w = (1.0e6f - 500.0f * bv0.w) * ai;
    G0.w = (cv0.w * cv0.w) * inv_h2 * ai;
    ai = 1.0f / (1.0e6f + 500.0f * bv1.x);
    Dc1.x = 2.0e6f * ai; Ey1.x = (1.0e6f - 500.0f * bv1.x) * ai;
    G1.x = (cv1.x * cv1.x) * inv_h2 * ai;
    ai = 1.0f / (1.0e6f + 500.0f * bv1.y);
    Dc1.y = 2.0e6f * ai; Ey1.y = (1.0e6f - 500.0f * bv1.y) * ai;
    G1.y = (cv1.y * cv1.y) * inv_h2 * ai;
    ai = 1.0f / (1.0e6f + 500.0f * bv1.z);
    Dc1.z = 2.0e6f * ai; Ey1.z = (1.0e6f - 500.0f * bv1.z) * ai;
    G1.z = (cv1.z * cv1.z) * inv_h2 * ai;
    ai = 1.0f / (1.0e6f + 500.0f * bv1.w);
    Dc1.w = 2.0e6f * ai; Ey1.w = (1.0e6f - 500.0f * bv1.w) * ai;
    G1.w = (cv1.w * cv1.w) * inv_h2 * ai;
    if (gr == SRC_X) {
      sm0.x = (gc + 0 == SRC_Y) ? 1.0f : 0.0f;
      sm0.y = (gc + 1 == SRC_Y) ? 1.0f : 0.0f;
      sm0.z = (gc + 2 == SRC_Y) ? 1.0f : 0.0f;
      sm0.w = (gc + 3 == SRC_Y) ? 1.0f : 0.0f;
      sm1.x = (gc + 4 == SRC_Y) ? 1.0f : 0.0f;
      sm1.y = (gc + 5 == SRC_Y) ? 1.0f : 0.0f;
      sm1.z = (gc + 6 == SRC_Y) ? 1.0f : 0.0f;
      sm1.w = (gc + 7 == SRC_Y) ? 1.0f : 0.0f;
    }
  }

  // ---- 3. Scatter y(t-1) into buf0 rows 1..44. Guard rows 0/45 are never
  //         read (row gating keeps lr==0 / lr==43 dead), so no zeroing. ----
  const int lo = (lr + 1) * LPITCH + 4 + 8 * lg;
  *(float4*)&buf0[lo] = yc0;
  *(float4*)&buf0[lo + 4] = yc1;
  __syncthreads();  // single prologue barrier

  float* ping = buf0;
  float* pong = buf1;

  // Pipelined output store state.
  float4 pv0 = z4, pv1 = z4;
  float* pop = out;  // dummy; only used when j>0

#define CELL(dst, up_, dn_, lf_, rt_, D_, E_, Gc_, y_, p_)              \
  {                                                                     \
    float s_ = fmaf(-4.0f, y_, (up_ + dn_) + (lf_ + rt_));              \
    dst = fmaf(Gc_, s_, fmaf(-E_, p_, D_ * y_));                        \
  }

#pragma unroll
  for (int j = 0; j < KSTEP; ++j) {
    const float xt = xs[j];
    float* op = out + obase + (t0 + j) * CELLS;

    // Store PREVIOUS step's output now (lgkm-only barriers never drain it;
    // it retires by kernel end / launch boundary).
    if (j > 0 && til) {
      *(float4*)(pop + gofs) = pv0;
      *(float4*)(pop + gofs + 4) = pv1;
    }

    // Trapezoid gating: step j only needs rows [j+1, 42-j]; j is
    // compile-time (full unroll) -> dead waves skip via execz.
    const bool alive = (lr >= j + 1) && (lr <= EXTR - 2 - j);
    if (alive) {
      // Left/right edge neighbors from register state of adjacent lanes.
      float lqw = __shfl_up(yc1.w, 1);
      lqw = (lg == 0) ? 0.0f : lqw;       // row's left edge neighbor is 0
      float rqx = __shfl_down(yc0.x, 1);  // lg==6 pulls zero lane lg==7 -> 0
      rqx = (lg == 7) ? 0.0f : rqx;       // lg==7's source may be exec-masked

      float4 up0 = *(float4*)&ping[lo - LPITCH];
      float4 up1 = *(float4*)&ping[lo - LPITCH + 4];
      float4 dn0 = *(float4*)&ping[lo + LPITCH];
      float4 dn1 = *(float4*)&ping[lo + LPITCH + 4];

      float4 val0, val1;
      CELL(val0.x, up0.x, dn0.x, lqw,    yc0.y, Dc0.x, Ey0.x, G0.x, yc0.x, yp0.x);
      CELL(val0.y, up0.y, dn0.y, yc0.x,  yc0.z, Dc0.y, Ey0.y, G0.y, yc0.y, yp0.y);
      CELL(val0.z, up0.z, dn0.z, yc0.y,  yc0.w, Dc0.z, Ey0.z, G0.z, yc0.z, yp0.z);
      CELL(val0.w, up0.w, dn0.w, yc0.z,  yc1.x, Dc0.w, Ey0.w, G0.w, yc0.w, yp0.w);
      CELL(val1.x, up1.x, dn1.x, yc0.w,  yc1.y, Dc1.x, Ey1.x, G1.x, yc1.x, yp1.x);
      CELL(val1.y, up1.y, dn1.y, yc1.x,  yc1.z, Dc1.y, Ey1.y, G1.y, yc1.y, yp1.y);
      CELL(val1.z, up1.z, dn1.z, yc1.y,  yc1.w, Dc1.z, Ey1.z, G1.z, yc1.z, yp1.z);
      CELL(val1.w, up1.w, dn1.w, yc1.z,  rqx,   Dc1.w, Ey1.w, G1.w, yc1.w, yp1.w);

      if (hs) {  // uniform: only blocks whose EXT tile contains the source
        val0.x = fmaf(sm0.x, xt, val0.x);
        val0.y = fmaf(sm0.y, xt, val0.y);
        val0.z = fmaf(sm0.z, xt, val0.z);
        val0.w = fmaf(sm0.w, xt, val0.w);
        val1.x = fmaf(sm1.x, xt, val1.x);
        val1.y = fmaf(sm1.y, xt, val1.y);
        val1.z = fmaf(sm1.z, xt, val1.z);
        val1.w = fmaf(sm1.w, xt, val1.w);
      }

      yp0 = yc0; yp1 = yc1;
      yc0 = val0; yc1 = val1;

      if (j < KSTEP - 1) {           // final step's LDS state is never read
        *(float4*)&pong[lo] = val0;  // lg==7 writes 0 into right pad
        *(float4*)&pong[lo + 4] = val1;
      }

      pv0 = val0; pv1 = val1;
    }
    pop = op;

    if (j < KSTEP - 1) {
      // lgkm-only barrier: LDS ping/pong visibility without vmcnt drain.
      asm volatile("s_waitcnt lgkmcnt(0)\n\ts_barrier" ::: "memory");
    }
    float* tmp = ping; ping = pong; pong = tmp;
  }
#undef CELL

  // Final step's output store (drains at kernel end).
  if (til) {
    *(float4*)(pop + gofs) = pv0;
    *(float4*)(pop + gofs + 4) = pv1;
  }
}

extern "C" void kernel_launch(void* const* d_in, const int* in_sizes, int n_in,
                              void* d_out, int out_size, void* d_ws,
                              size_t ws_size, hipStream_t stream) {
  const float* x = (const float*)d_in[0];  // [B, T, 1]
  const float* c = (const float*)d_in[1];  // [192,192]
  const float* b = (const float*)d_in[2];  // [192,192]
  float* out = (float*)d_out;              // [B, T, 192, 192]

  dim3 grid(NYg / TSC, NXg / TSR, BATCH);  // 8 x 16 x 4 = 512 blocks = 2/CU
  for (int t0 = 0; t0 < TSTEPS; t0 += KSTEP) {
    wave_tile_kernel<<<grid, NTHREADS, 0, stream>>>(c, b, x, out, t0);
  }
}